// Round 1
// baseline (1358.544 us; speedup 1.0000x reference)
//
#include <hip/hip_runtime.h>
#include <hip/hip_bf16.h>

// Problem constants (from reference)
#define NN 100000      // nodes
#define FF 128         // F_IN
#define HH 64          // HID
#define BN_EPS 1e-5f

// ---------------- dtype detection (int64 vs int32 edge/batch) ----------------
__global__ void k_detect(const unsigned* __restrict__ ei, int* __restrict__ flag) {
    if (threadIdx.x == 0 && blockIdx.x == 0) {
        unsigned o = 0;
        for (int i = 1; i < 32; i += 2) o |= ei[i];   // high words if int64
        *flag = (o == 0) ? 1 : 0;                      // 1 => int64
    }
}

__device__ __forceinline__ int load_idx(const void* p, int i, int is64) {
    return is64 ? (int)((const long long*)p)[i] : ((const int*)p)[i];
}

// ---------------- degree count ----------------
__global__ void k_count(const void* __restrict__ ei, int E, const int* __restrict__ flag,
                        int* __restrict__ counts) {
    int e = blockIdx.x * blockDim.x + threadIdx.x;
    if (e >= E) return;
    int is64 = *flag;
    int d = load_idx(ei, E + e, is64);   // dst row is second half
    atomicAdd(&counts[d], 1);
}

// ---------------- dinv + per-graph node counts ----------------
__global__ void k_dinv(const int* __restrict__ counts, float* __restrict__ dinv,
                       const void* __restrict__ bat, const int* __restrict__ flag,
                       int* __restrict__ gcnt, int N) {
    int i = blockIdx.x * blockDim.x + threadIdx.x;
    if (i >= N) return;
    float deg = (float)counts[i] + 1.0f;
    dinv[i] = rsqrtf(deg);
    int is64 = *flag;
    int b = load_idx(bat, i, is64);
    atomicAdd(&gcnt[b], 1);
}

// ---------------- 3-kernel exclusive scan (chunk = 512) ----------------
__global__ void k_scan1(const int* __restrict__ counts, int* __restrict__ partial, int N) {
    __shared__ int s[512];
    int t = threadIdx.x;
    int i = blockIdx.x * 512 + t;
    int v = (i < N) ? counts[i] : 0;
    s[t] = v; __syncthreads();
    for (int off = 256; off; off >>= 1) {
        if (t < off) s[t] += s[t + off];
        __syncthreads();
    }
    if (t == 0) partial[blockIdx.x] = s[0];
}

__global__ void k_scan2(int* __restrict__ partial, int nch) {
    __shared__ int s[256];
    int t = threadIdx.x;
    int v = (t < nch) ? partial[t] : 0;
    s[t] = v; __syncthreads();
    for (int off = 1; off < 256; off <<= 1) {
        int add = (t >= off) ? s[t - off] : 0;
        __syncthreads();
        s[t] += add;
        __syncthreads();
    }
    if (t < nch) partial[t] = s[t] - v;   // exclusive
}

__global__ void k_scan3(const int* __restrict__ counts, const int* __restrict__ partial,
                        int* __restrict__ rp, int N, int E) {
    __shared__ int s[512];
    int t = threadIdx.x;
    int i = blockIdx.x * 512 + t;
    int v = (i < N) ? counts[i] : 0;
    s[t] = v; __syncthreads();
    for (int off = 1; off < 512; off <<= 1) {
        int add = (t >= off) ? s[t - off] : 0;
        __syncthreads();
        s[t] += add;
        __syncthreads();
    }
    if (i < N) rp[i] = partial[blockIdx.x] + s[t] - v;
    if (i == N) rp[N] = E;
}

// ---------------- CSR fill: packed {src, w} ----------------
__global__ void k_fill(const void* __restrict__ ei, int E, const int* __restrict__ flag,
                       const float* __restrict__ dinv, const int* __restrict__ rp,
                       int* __restrict__ fillcnt, int2* __restrict__ cw) {
    int e = blockIdx.x * blockDim.x + threadIdx.x;
    if (e >= E) return;
    int is64 = *flag;
    int s = load_idx(ei, e, is64);
    int d = load_idx(ei, E + e, is64);
    float w = dinv[s] * dinv[d];
    int pos = rp[d] + atomicAdd(&fillcnt[d], 1);
    int2 p; p.x = s; p.y = __float_as_int(w);
    cw[pos] = p;
}

// ---------------- BN constant folding ----------------
__global__ void k_prep(const float* b1, const float* g1, const float* be1,
                       const float* m1, const float* v1,
                       const float* b2, const float* g2, const float* be2,
                       const float* m2, const float* v2,
                       float* sc1, float* sh1, float* sc2, float* sh2) {
    int f = threadIdx.x;
    if (f < HH) {
        float s1 = g1[f] * rsqrtf(v1[f] + BN_EPS);
        sc1[f] = s1; sh1[f] = (b1[f] - m1[f]) * s1 + be1[f];
        float s2 = g2[f] * rsqrtf(v2[f] + BN_EPS);
        sc2[f] = s2; sh2[f] = (b2[f] - m2[f]) * s2 + be2[f];
    }
}

// ---------------- dense GEMM: out[n][f] = sum_k x[n][k] * W[f][k] ----------------
template <int K, int NPB>
__global__ void k_gemm(const float* __restrict__ x, const float* __restrict__ W,
                       float* __restrict__ out, int N) {
    __shared__ float wT[K * (HH + 1)];
    __shared__ float xs[NPB * K];
    const int TB = NPB * 64;
    int t = threadIdx.x;
    for (int idx = t; idx < K * HH; idx += TB) {
        int f = idx / K, k = idx % K;
        wT[k * (HH + 1) + f] = W[idx];
    }
    int nb = blockIdx.x * NPB;
    for (int idx = t; idx < NPB * K; idx += TB) {
        int gi = nb * K + idx;
        xs[idx] = (gi < N * K) ? x[gi] : 0.0f;
    }
    __syncthreads();
    int f = t & 63, nl = t >> 6;
    float acc = 0.0f;
#pragma unroll
    for (int k = 0; k < K; k++)
        acc += xs[nl * K + k] * wT[k * (HH + 1) + f];
    int n = nb + nl;
    if (n < N) out[n * HH + f] = acc;
}

// ---------------- aggregation (wave per node) + BN + ReLU (+pool fuse in L2) ----
template <int LAYER>
__global__ void k_agg(const float* __restrict__ h, const int2* __restrict__ cw,
                      const int* __restrict__ rp, const float* __restrict__ dinv,
                      const float* __restrict__ sc, const float* __restrict__ sh,
                      float* __restrict__ out,
                      const void* __restrict__ bat, const int* __restrict__ flag,
                      const float* __restrict__ Wl, float* __restrict__ gsum, int N) {
    int wid = (int)((blockIdx.x * blockDim.x + threadIdx.x) >> 6);
    int f = threadIdx.x & 63;
    if (wid >= N) return;
    float di = dinv[wid];
    float acc = h[wid * HH + f] * di * di;
    int s = rp[wid], e = rp[wid + 1];
    int j = s;
    for (; j + 1 < e; j += 2) {
        int2 p0 = cw[j], p1 = cw[j + 1];
        acc += __int_as_float(p0.y) * h[p0.x * HH + f];
        acc += __int_as_float(p1.y) * h[p1.x * HH + f];
    }
    if (j < e) {
        int2 p = cw[j];
        acc += __int_as_float(p.y) * h[p.x * HH + f];
    }
    float v = fmaxf(acc * sc[f] + sh[f], 0.0f);
    if (LAYER == 1) {
        out[wid * HH + f] = v;
    } else {
        float tval = v * Wl[f];
        for (int off = 32; off; off >>= 1) tval += __shfl_down(tval, off);
        if (f == 0) {
            int is64 = *flag;
            int b = load_idx(bat, wid, is64);
            atomicAdd(&gsum[b], tval);
        }
    }
}

// ---------------- final: mean + linear bias ----------------
__global__ void k_final(const float* __restrict__ gsum, const int* __restrict__ gcnt,
                        const float* __restrict__ bl, float* __restrict__ outp, int G) {
    int g = blockIdx.x * blockDim.x + threadIdx.x;
    if (g < G) outp[g] = gsum[g] / fmaxf((float)gcnt[g], 1.0f) + bl[0];
}

extern "C" void kernel_launch(void* const* d_in, const int* in_sizes, int n_in,
                              void* d_out, int out_size, void* d_ws, size_t ws_size,
                              hipStream_t stream) {
    const float* x   = (const float*)d_in[0];
    const void*  ei  = d_in[1];
    const void*  bat = d_in[2];
    const float* W1  = (const float*)d_in[3];
    const float* b1  = (const float*)d_in[4];
    const float* g1  = (const float*)d_in[5];
    const float* be1 = (const float*)d_in[6];
    const float* m1  = (const float*)d_in[7];
    const float* v1  = (const float*)d_in[8];
    const float* W2  = (const float*)d_in[9];
    const float* b2  = (const float*)d_in[10];
    const float* g2  = (const float*)d_in[11];
    const float* be2 = (const float*)d_in[12];
    const float* m2  = (const float*)d_in[13];
    const float* v2  = (const float*)d_in[14];
    const float* Wl  = (const float*)d_in[15];
    const float* bl  = (const float*)d_in[16];
    float* outp = (float*)d_out;

    const int N = NN;
    const int E = in_sizes[1] / 2;
    const int G = out_size;

    // workspace carve-up (256B aligned)
    char* base = (char*)d_ws;
    size_t off = 0;
    auto alloc = [&](size_t bytes) { void* p = base + off; off = (off + bytes + 255) & ~(size_t)255; return p; };
    int*   flag    = (int*)  alloc(16);
    float* dinv    = (float*)alloc((size_t)N * 4);
    int*   counts  = (int*)  alloc((size_t)N * 4);
    int*   rp      = (int*)  alloc(((size_t)N + 1) * 4);
    int*   fillcnt = (int*)  alloc((size_t)N * 4);
    int*   partial = (int*)  alloc(1024);
    float* sc1     = (float*)alloc(HH * 4);
    float* sh1     = (float*)alloc(HH * 4);
    float* sc2     = (float*)alloc(HH * 4);
    float* sh2     = (float*)alloc(HH * 4);
    float* gsum    = (float*)alloc((size_t)G * 4);
    int*   gcnt    = (int*)  alloc((size_t)G * 4);
    int2*  cw      = (int2*) alloc((size_t)E * 8);
    float* bufA    = (float*)alloc((size_t)N * HH * 4);   // h1, later h2
    float* bufB    = (float*)alloc((size_t)N * HH * 4);   // h2in
    (void)ws_size;

    // zero accumulators (fresh every call)
    hipMemsetAsync(counts, 0, (size_t)N * 4, stream);
    hipMemsetAsync(fillcnt, 0, (size_t)N * 4, stream);
    hipMemsetAsync(gsum, 0, (size_t)G * 4, stream);
    hipMemsetAsync(gcnt, 0, (size_t)G * 4, stream);

    k_detect<<<1, 64, 0, stream>>>((const unsigned*)ei, flag);

    int eb = (E + 255) / 256;
    k_count<<<eb, 256, 0, stream>>>(ei, E, flag, counts);

    int nb = (N + 255) / 256;
    k_dinv<<<nb, 256, 0, stream>>>(counts, dinv, bat, flag, gcnt, N);

    int nch = (N + 511) / 512;
    k_scan1<<<nch, 512, 0, stream>>>(counts, partial, N);
    k_scan2<<<1, 256, 0, stream>>>(partial, nch);
    k_scan3<<<nch, 512, 0, stream>>>(counts, partial, rp, N, E);

    k_fill<<<eb, 256, 0, stream>>>(ei, E, flag, dinv, rp, fillcnt, cw);

    k_prep<<<1, 64, 0, stream>>>(b1, g1, be1, m1, v1, b2, g2, be2, m2, v2,
                                 sc1, sh1, sc2, sh2);

    // layer 1
    k_gemm<FF, 8><<<(N + 7) / 8, 512, 0, stream>>>(x, W1, bufA, N);
    k_agg<1><<<(N + 3) / 4, 256, 0, stream>>>(bufA, cw, rp, dinv, sc1, sh1, bufB,
                                              bat, flag, Wl, gsum, N);
    // layer 2
    k_gemm<HH, 8><<<(N + 7) / 8, 512, 0, stream>>>(bufB, W2, bufA, N);
    k_agg<2><<<(N + 3) / 4, 256, 0, stream>>>(bufA, cw, rp, dinv, sc2, sh2, nullptr,
                                              bat, flag, Wl, gsum, N);

    k_final<<<1, 256, 0, stream>>>(gsum, gcnt, bl, outp, G);
}

// Round 2
// 1266.926 us; speedup vs baseline: 1.0723x; 1.0723x over previous
//
#include <hip/hip_runtime.h>
#include <hip/hip_bf16.h>

// Problem constants (from reference)
#define NN 100000      // nodes
#define FF 128         // F_IN
#define HH 64          // HID
#define BN_EPS 1e-5f

// ---------------- dtype detection (int64 vs int32 edge/batch) ----------------
__global__ void k_detect(const unsigned* __restrict__ ei, int* __restrict__ flag) {
    if (threadIdx.x == 0 && blockIdx.x == 0) {
        unsigned o = 0;
        for (int i = 1; i < 32; i += 2) o |= ei[i];   // high words if int64
        *flag = (o == 0) ? 1 : 0;                      // 1 => int64
    }
}

__device__ __forceinline__ int load_idx(const void* p, int i, int is64) {
    return is64 ? (int)((const long long*)p)[i] : ((const int*)p)[i];
}

// ---------------- degree count ----------------
__global__ void k_count(const void* __restrict__ ei, int E, const int* __restrict__ flag,
                        int* __restrict__ counts) {
    int e = blockIdx.x * blockDim.x + threadIdx.x;
    if (e >= E) return;
    int is64 = *flag;
    int d = load_idx(ei, E + e, is64);   // dst row is second half
    atomicAdd(&counts[d], 1);
}

// ---------------- dinv + per-graph node counts ----------------
__global__ void k_dinv(const int* __restrict__ counts, float* __restrict__ dinv,
                       const void* __restrict__ bat, const int* __restrict__ flag,
                       int* __restrict__ gcnt, int N) {
    int i = blockIdx.x * blockDim.x + threadIdx.x;
    if (i >= N) return;
    float deg = (float)counts[i] + 1.0f;
    dinv[i] = rsqrtf(deg);
    int is64 = *flag;
    int b = load_idx(bat, i, is64);
    atomicAdd(&gcnt[b], 1);
}

// ---------------- 3-kernel exclusive scan (chunk = 512) ----------------
__global__ void k_scan1(const int* __restrict__ counts, int* __restrict__ partial, int N) {
    __shared__ int s[512];
    int t = threadIdx.x;
    int i = blockIdx.x * 512 + t;
    int v = (i < N) ? counts[i] : 0;
    s[t] = v; __syncthreads();
    for (int off = 256; off; off >>= 1) {
        if (t < off) s[t] += s[t + off];
        __syncthreads();
    }
    if (t == 0) partial[blockIdx.x] = s[0];
}

__global__ void k_scan2(int* __restrict__ partial, int nch) {
    __shared__ int s[256];
    int t = threadIdx.x;
    int v = (t < nch) ? partial[t] : 0;
    s[t] = v; __syncthreads();
    for (int off = 1; off < 256; off <<= 1) {
        int add = (t >= off) ? s[t - off] : 0;
        __syncthreads();
        s[t] += add;
        __syncthreads();
    }
    if (t < nch) partial[t] = s[t] - v;   // exclusive
}

__global__ void k_scan3(const int* __restrict__ counts, const int* __restrict__ partial,
                        int* __restrict__ rp, int N, int E) {
    __shared__ int s[512];
    int t = threadIdx.x;
    int i = blockIdx.x * 512 + t;
    int v = (i < N) ? counts[i] : 0;
    s[t] = v; __syncthreads();
    for (int off = 1; off < 512; off <<= 1) {
        int add = (t >= off) ? s[t - off] : 0;
        __syncthreads();
        s[t] += add;
        __syncthreads();
    }
    if (i < N) rp[i] = partial[blockIdx.x] + s[t] - v;
    if (i == N) rp[N] = E;
}

// ---------------- CSR fill: packed {src, w} ----------------
__global__ void k_fill(const void* __restrict__ ei, int E, const int* __restrict__ flag,
                       const float* __restrict__ dinv, const int* __restrict__ rp,
                       int* __restrict__ fillcnt, int2* __restrict__ cw) {
    int e = blockIdx.x * blockDim.x + threadIdx.x;
    if (e >= E) return;
    int is64 = *flag;
    int s = load_idx(ei, e, is64);
    int d = load_idx(ei, E + e, is64);
    float w = dinv[s] * dinv[d];
    int pos = rp[d] + atomicAdd(&fillcnt[d], 1);
    int2 p; p.x = s; p.y = __float_as_int(w);
    cw[pos] = p;
}

// ---------------- BN constant folding ----------------
__global__ void k_prep(const float* b1, const float* g1, const float* be1,
                       const float* m1, const float* v1,
                       const float* b2, const float* g2, const float* be2,
                       const float* m2, const float* v2,
                       float* sc1, float* sh1, float* sc2, float* sh2) {
    int f = threadIdx.x;
    if (f < HH) {
        float s1 = g1[f] * rsqrtf(v1[f] + BN_EPS);
        sc1[f] = s1; sh1[f] = (b1[f] - m1[f]) * s1 + be1[f];
        float s2 = g2[f] * rsqrtf(v2[f] + BN_EPS);
        sc2[f] = s2; sh2[f] = (b2[f] - m2[f]) * s2 + be2[f];
    }
}

// ---------------- dense GEMM: out[n][f] = sum_k x[n][k] * W[f][k] ----------------
template <int K, int NPB>
__global__ void k_gemm(const float* __restrict__ x, const float* __restrict__ W,
                       float* __restrict__ out, int N) {
    __shared__ float wT[K * (HH + 1)];
    __shared__ float xs[NPB * K];
    const int TB = NPB * 64;
    int t = threadIdx.x;
    for (int idx = t; idx < K * HH; idx += TB) {
        int f = idx / K, k = idx % K;
        wT[k * (HH + 1) + f] = W[idx];
    }
    int nb = blockIdx.x * NPB;
    for (int idx = t; idx < NPB * K; idx += TB) {
        int gi = nb * K + idx;
        xs[idx] = (gi < N * K) ? x[gi] : 0.0f;
    }
    __syncthreads();
    int f = t & 63, nl = t >> 6;
    float acc = 0.0f;
#pragma unroll
    for (int k = 0; k < K; k++)
        acc += xs[nl * K + k] * wT[k * (HH + 1) + f];
    int n = nb + nl;
    if (n < N) out[n * HH + f] = acc;
}

// ---------------- aggregation (wave per node, 4 edges/iter x unroll 2) --------
// Lane layout: q = lane>>4 (edge slot within group), fl = lane&15 (float4 chunk
// of the 64-float feature row). One wave issues 8 independent row gathers per
// loop iteration -> high memory-level parallelism (we are latency-bound).
template <int LAYER>
__global__ void k_agg(const float* __restrict__ h, const int2* __restrict__ cw,
                      const int* __restrict__ rp, const float* __restrict__ dinv,
                      const float* __restrict__ sc, const float* __restrict__ sh,
                      float* __restrict__ out,
                      const void* __restrict__ bat, const int* __restrict__ flag,
                      const float* __restrict__ Wl, float* __restrict__ gsum, int N) {
    int wid = (int)((blockIdx.x * blockDim.x + threadIdx.x) >> 6);
    if (wid >= N) return;
    int lane = threadIdx.x & 63;
    int q = lane >> 4;       // which edge within the 4-edge group
    int fl = lane & 15;      // which float4 of the row
    const float4* __restrict__ h4 = (const float4*)h;

    int s = rp[wid], e = rp[wid + 1];
    float ax = 0.f, ay = 0.f, az = 0.f, aw = 0.f;
    if (e > s) {
        int last = e - 1;
        for (int j0 = s; j0 < e; j0 += 8) {
            int jj0 = j0 + q;
            int jj1 = j0 + 4 + q;
            int2 p0 = cw[jj0 < last ? jj0 : last];
            int2 p1 = cw[jj1 < last ? jj1 : last];
            float w0 = (jj0 < e) ? __int_as_float(p0.y) : 0.f;
            float w1 = (jj1 < e) ? __int_as_float(p1.y) : 0.f;
            float4 r0 = h4[p0.x * 16 + fl];
            float4 r1 = h4[p1.x * 16 + fl];
            ax += w0 * r0.x + w1 * r1.x;
            ay += w0 * r0.y + w1 * r1.y;
            az += w0 * r0.z + w1 * r1.z;
            aw += w0 * r0.w + w1 * r1.w;
        }
    }
    // combine the 4 edge-partitions (lanes differing in bits 4,5)
    ax += __shfl_xor(ax, 16); ay += __shfl_xor(ay, 16);
    az += __shfl_xor(az, 16); aw += __shfl_xor(aw, 16);
    ax += __shfl_xor(ax, 32); ay += __shfl_xor(ay, 32);
    az += __shfl_xor(az, 32); aw += __shfl_xor(aw, 32);

    // self-loop term (added once, post-reduce)
    float di = dinv[wid];
    float di2 = di * di;
    float4 sr = h4[wid * 16 + fl];
    ax += di2 * sr.x; ay += di2 * sr.y; az += di2 * sr.z; aw += di2 * sr.w;

    // BN + ReLU on this lane's 4 features
    int f0 = fl * 4;
    float vx = fmaxf(ax * sc[f0 + 0] + sh[f0 + 0], 0.f);
    float vy = fmaxf(ay * sc[f0 + 1] + sh[f0 + 1], 0.f);
    float vz = fmaxf(az * sc[f0 + 2] + sh[f0 + 2], 0.f);
    float vw = fmaxf(aw * sc[f0 + 3] + sh[f0 + 3], 0.f);

    if (LAYER == 1) {
        if (lane < 16) {
            float4 o; o.x = vx; o.y = vy; o.z = vz; o.w = vw;
            ((float4*)out)[wid * 16 + fl] = o;
        }
    } else {
        float tval = vx * Wl[f0] + vy * Wl[f0 + 1] + vz * Wl[f0 + 2] + vw * Wl[f0 + 3];
        tval += __shfl_xor(tval, 1);
        tval += __shfl_xor(tval, 2);
        tval += __shfl_xor(tval, 4);
        tval += __shfl_xor(tval, 8);
        if (lane == 0) {
            int is64 = *flag;
            int b = load_idx(bat, wid, is64);
            atomicAdd(&gsum[b], tval);
        }
    }
}

// ---------------- final: mean + linear bias ----------------
__global__ void k_final(const float* __restrict__ gsum, const int* __restrict__ gcnt,
                        const float* __restrict__ bl, float* __restrict__ outp, int G) {
    int g = blockIdx.x * blockDim.x + threadIdx.x;
    if (g < G) outp[g] = gsum[g] / fmaxf((float)gcnt[g], 1.0f) + bl[0];
}

extern "C" void kernel_launch(void* const* d_in, const int* in_sizes, int n_in,
                              void* d_out, int out_size, void* d_ws, size_t ws_size,
                              hipStream_t stream) {
    const float* x   = (const float*)d_in[0];
    const void*  ei  = d_in[1];
    const void*  bat = d_in[2];
    const float* W1  = (const float*)d_in[3];
    const float* b1  = (const float*)d_in[4];
    const float* g1  = (const float*)d_in[5];
    const float* be1 = (const float*)d_in[6];
    const float* m1  = (const float*)d_in[7];
    const float* v1  = (const float*)d_in[8];
    const float* W2  = (const float*)d_in[9];
    const float* b2  = (const float*)d_in[10];
    const float* g2  = (const float*)d_in[11];
    const float* be2 = (const float*)d_in[12];
    const float* m2  = (const float*)d_in[13];
    const float* v2  = (const float*)d_in[14];
    const float* Wl  = (const float*)d_in[15];
    const float* bl  = (const float*)d_in[16];
    float* outp = (float*)d_out;

    const int N = NN;
    const int E = in_sizes[1] / 2;
    const int G = out_size;

    // workspace carve-up (256B aligned)
    char* base = (char*)d_ws;
    size_t off = 0;
    auto alloc = [&](size_t bytes) { void* p = base + off; off = (off + bytes + 255) & ~(size_t)255; return p; };
    int*   flag    = (int*)  alloc(16);
    float* dinv    = (float*)alloc((size_t)N * 4);
    int*   counts  = (int*)  alloc((size_t)N * 4);
    int*   rp      = (int*)  alloc(((size_t)N + 1) * 4);
    int*   fillcnt = (int*)  alloc((size_t)N * 4);
    int*   partial = (int*)  alloc(1024);
    float* sc1     = (float*)alloc(HH * 4);
    float* sh1     = (float*)alloc(HH * 4);
    float* sc2     = (float*)alloc(HH * 4);
    float* sh2     = (float*)alloc(HH * 4);
    float* gsum    = (float*)alloc((size_t)G * 4);
    int*   gcnt    = (int*)  alloc((size_t)G * 4);
    int2*  cw      = (int2*) alloc((size_t)E * 8);
    float* bufA    = (float*)alloc((size_t)N * HH * 4);   // h1, later h2
    float* bufB    = (float*)alloc((size_t)N * HH * 4);   // h2in
    (void)ws_size;

    // zero accumulators (fresh every call)
    hipMemsetAsync(counts, 0, (size_t)N * 4, stream);
    hipMemsetAsync(fillcnt, 0, (size_t)N * 4, stream);
    hipMemsetAsync(gsum, 0, (size_t)G * 4, stream);
    hipMemsetAsync(gcnt, 0, (size_t)G * 4, stream);

    k_detect<<<1, 64, 0, stream>>>((const unsigned*)ei, flag);

    int eb = (E + 255) / 256;
    k_count<<<eb, 256, 0, stream>>>(ei, E, flag, counts);

    int nb = (N + 255) / 256;
    k_dinv<<<nb, 256, 0, stream>>>(counts, dinv, bat, flag, gcnt, N);

    int nch = (N + 511) / 512;
    k_scan1<<<nch, 512, 0, stream>>>(counts, partial, N);
    k_scan2<<<1, 256, 0, stream>>>(partial, nch);
    k_scan3<<<nch, 512, 0, stream>>>(counts, partial, rp, N, E);

    k_fill<<<eb, 256, 0, stream>>>(ei, E, flag, dinv, rp, fillcnt, cw);

    k_prep<<<1, 64, 0, stream>>>(b1, g1, be1, m1, v1, b2, g2, be2, m2, v2,
                                 sc1, sh1, sc2, sh2);

    // layer 1
    k_gemm<FF, 8><<<(N + 7) / 8, 512, 0, stream>>>(x, W1, bufA, N);
    k_agg<1><<<(N + 3) / 4, 256, 0, stream>>>(bufA, cw, rp, dinv, sc1, sh1, bufB,
                                              bat, flag, Wl, gsum, N);
    // layer 2
    k_gemm<HH, 8><<<(N + 7) / 8, 512, 0, stream>>>(bufB, W2, bufA, N);
    k_agg<2><<<(N + 3) / 4, 256, 0, stream>>>(bufA, cw, rp, dinv, sc2, sh2, nullptr,
                                              bat, flag, Wl, gsum, N);

    k_final<<<1, 256, 0, stream>>>(gsum, gcnt, bl, outp, G);
}